// Round 4
// baseline (538.398 us; speedup 1.0000x reference)
//
#include <hip/hip_runtime.h>
#include <cmath>

typedef __attribute__((ext_vector_type(8))) short bf16x8;
typedef __attribute__((ext_vector_type(4))) float f32x4;
typedef unsigned short u16;

struct __align__(8) us4 { u16 x, y, z, w; };

__device__ __forceinline__ u16 f2bf(float f) {
    union { float f; unsigned u; } v; v.f = f;
    unsigned u = v.u;
    u += 0x7fffu + ((u >> 16) & 1u);   // RNE
    return (u16)(u >> 16);
}
__device__ __forceinline__ float bf2f(u16 h) {
    union { unsigned u; float f; } v; v.u = ((unsigned)h) << 16;
    return v.f;
}
__device__ __forceinline__ f32x4 mfma16(bf16x8 a, bf16x8 b, f32x4 c) {
    return __builtin_amdgcn_mfma_f32_16x16x32_bf16(a, b, c, 0, 0, 0);
}
__device__ __forceinline__ void ld_lds16(const u16* g, u16* l) {
    __builtin_amdgcn_global_load_lds(
        (const __attribute__((address_space(1))) unsigned int*)g,
        (__attribute__((address_space(3))) unsigned int*)l, 16, 0, 0);
}

#define VMCNT(n) asm volatile("s_waitcnt vmcnt(" #n ")" ::: "memory")
#define LGKM0()  do { asm volatile("s_waitcnt lgkmcnt(0)" ::: "memory"); \
                      __builtin_amdgcn_sched_barrier(0); } while (0)

// ---------------- x -> CatA right half (bf16) + zero qv/kv ----------------
__global__ __launch_bounds__(256) void cvtx(const float* __restrict__ in,
                                            u16* __restrict__ CatA, float* __restrict__ qkz) {
    int i = blockIdx.x * 256 + threadIdx.x;         // over 3145728 float4 groups
    float4 f = reinterpret_cast<const float4*>(in)[i];
    us4 o; o.x = f2bf(f.x); o.y = f2bf(f.y); o.z = f2bf(f.z); o.w = f2bf(f.w);
    int row = i / 192, col = (i % 192) * 4;
    *reinterpret_cast<us4*>(CatA + (size_t)row * 1536 + 768 + col) = o;
    if (i < 8192) reinterpret_cast<float4*>(qkz)[i] = float4{0.f, 0.f, 0.f, 0.f};
}

// ---------------- 7 weight converts in one dispatch ----------------
struct WCvt { const float* s[7]; u16* d[7]; int ld[7]; };
__global__ __launch_bounds__(256) void cvtw(WCvt w) {
    int wi = blockIdx.y;
    int i = blockIdx.x * 256 + threadIdx.x;         // over 147456 float4 groups
    float4 f = reinterpret_cast<const float4*>(w.s[wi])[i];
    us4 o; o.x = f2bf(f.x); o.y = f2bf(f.y); o.z = f2bf(f.z); o.w = f2bf(f.w);
    int row = i / 192, col = (i % 192) * 4;
    *reinterpret_cast<us4*>(w.d[wi] + (size_t)row * w.ld[wi] + col) = o;
}

// =====================================================================
// Deep-pipeline GEMM engine: BM=256 x BN=128, BK=64, 512 thr (8 waves,
// 4M x 2N, 64x64 per wave). 3-deep K-tile LDS ring (144 KB, 1 blk/CU).
// Per K-tile: 4 phases {ds_read (8/4/4/0 b128); stage 1 unit; barrier;
// lgkmcnt(0)+sched_barrier; setprio(1); 8 MFMA; setprio(0); barrier}.
// Units of K-tile T+2 staged during T -> boundary wait vmcnt(6), NEVER
// drains in steady state; only the last boundary uses vmcnt(0).
// Race-freedom: slot (T+2)%3 != slots of T, T+1 (reads); stage issue
// ordered after the boundary barrier => after all reads of slot (T-1).
// Swizzle: round-0 proven pair (src chunk = (t&7)^((t>>3)&7), read
// chunk = (quad+4h)^(lm&7)) -> 0 bank conflicts.
// =====================================================================
enum { EPI_FPT = 0, EPI_Y, EPI_GATES, EPI_OUT };

struct Epi {
    const float* b1; const float* b2; const float* b3; const float* b4;
    const float* wq; const float* wk; float* qv; float* kv;   // FPT
    u16* fpT;
    u16* catA;                                                 // Y
    const u16* xb;        // CatA+768 (stride 1536)
    u16* ub_o; u16* rxb_o;                                     // GATES
    const u16* ub; float* of;                                  // OUT
};

struct GArgs {
    const u16 *A1, *B1, *A2, *B2;
    int nt1, nt2, ldA1, ldB1, ldA2, ldB2;
    size_t zA, zB;
    Epi e;
};

template<int EPI>
__device__ __forceinline__ void gk_body(const GArgs& g) {
    __shared__ __align__(16) u16 lA[3 * 16384];   // 96 KB: 3 x (256 x 64)
    __shared__ __align__(16) u16 lB[3 * 8192];    // 48 KB: 3 x (128 x 64)

    const int t = threadIdx.x;
    const int w = t >> 6, lane = t & 63, lm = lane & 15, quad = lane >> 4;
    const int wm = w >> 1, wn = w & 1;            // 4 M-waves x 2 N-waves
    const int row0 = blockIdx.x * 256;
    int col0, grp = 0;
    if constexpr (EPI == EPI_GATES) { grp = blockIdx.y / 6; col0 = (blockIdx.y % 6) * 128; }
    else col0 = blockIdx.y * 128;

    const u16* A1p = g.A1 + (size_t)blockIdx.z * g.zA;
    const u16* B1p = g.B1 + (size_t)blockIdx.z * g.zB;
    if constexpr (EPI == EPI_GATES) B1p += (size_t)grp * (768 * 1536);
    const int nt1 = g.nt1;
    const int NT = g.nt1 + g.nt2;

    // staging map: thread t -> row srow = t>>3 (0..63), 16B chunk (t&7),
    // source chunk pre-swizzled by row&7 so the linear global_load_lds
    // dest holds the layout the swizzled reader expects.
    const int srow = t >> 3;
    const int scol = ((t & 7) ^ (srow & 7)) * 8;  // u16 units

    auto stageA = [&](int ti, int slot, int u) {  // u: 0 = rows 0..127, 1 = 128..255
        const u16* S; int ld_, kk;
        if (ti < nt1) { S = A1p; ld_ = g.ldA1; kk = ti * 64; }
        else          { S = g.A2; ld_ = g.ldA2; kk = (ti - nt1) * 64; }
        const u16* gp = S + (size_t)(row0 + u * 128 + srow) * ld_ + kk + scol;
        u16* d = lA + slot * 16384 + u * 8192 + w * 512;
        ld_lds16(gp, d);                               // rows srow (0..63)
        ld_lds16(gp + (size_t)64 * ld_, d + 4096);     // rows srow+64
    };
    auto stageB = [&](int ti, int slot, int v) {  // v: 0 = rows 0..63, 1 = 64..127
        const u16* S; int ld_, kk;
        if (ti < nt1) { S = B1p; ld_ = g.ldB1; kk = ti * 64; }
        else          { S = g.B2; ld_ = g.ldB2; kk = (ti - nt1) * 64; }
        const u16* gp = S + (size_t)(col0 + v * 64 + srow) * ld_ + kk + scol;
        ld_lds16(gp, lB + slot * 8192 + v * 4096 + w * 512);
    };

    // compute map
    const int rw0 = wm * 64, cw0 = wn * 64;
    const int ch0 = ((quad) ^ (lm & 7)) * 8;
    const int ch1 = ((quad + 4) ^ (lm & 7)) * 8;
    int laB[4], lbB[4];
#pragma unroll
    for (int i = 0; i < 4; i++) laB[i] = (rw0 + i * 16 + lm) * 64;
#pragma unroll
    for (int j = 0; j < 4; j++) lbB[j] = (cw0 + j * 16 + lm) * 64;

    f32x4 acc[4][4] = {};

    // prologue: K-tiles 0,1 fully staged (12 loads); wait K0 resident (6 fly)
    stageA(0, 0, 0); stageA(0, 0, 1); stageB(0, 0, 0); stageB(0, 0, 1);
    stageA(1, 1, 0); stageA(1, 1, 1); stageB(1, 1, 0); stageB(1, 1, 1);
    VMCNT(6);
    __builtin_amdgcn_s_barrier();
    __builtin_amdgcn_sched_barrier(0);

    int scur = 0, spre = 2;                       // T%3, (T+2)%3
    for (int T = 0; T < NT; ++T) {
        const u16* bA = lA + scur * 16384;
        const u16* bB = lB + scur * 8192;
        const bool pf = (T + 2) < NT;
        bf16x8 a0[4], a1[4], b0[4], b1[4];

        // ---- phase 0: read A(k0)+B(k0) [8]; stage A-unit0(T+2); MFMA (k0, j=0,1)
#pragma unroll
        for (int i = 0; i < 4; i++) a0[i] = *reinterpret_cast<const bf16x8*>(bA + laB[i] + ch0);
#pragma unroll
        for (int j = 0; j < 4; j++) b0[j] = *reinterpret_cast<const bf16x8*>(bB + lbB[j] + ch0);
        if (pf) stageA(T + 2, spre, 0);
        __builtin_amdgcn_s_barrier();
        LGKM0();
        __builtin_amdgcn_s_setprio(1);
#pragma unroll
        for (int i = 0; i < 4; i++) {
            acc[i][0] = mfma16(a0[i], b0[0], acc[i][0]);
            acc[i][1] = mfma16(a0[i], b0[1], acc[i][1]);
        }
        __builtin_amdgcn_s_setprio(0);
        __builtin_amdgcn_s_barrier();

        // ---- phase 1: read A(k1) [4]; stage A-unit1(T+2); MFMA (k0, j=2,3)
#pragma unroll
        for (int i = 0; i < 4; i++) a1[i] = *reinterpret_cast<const bf16x8*>(bA + laB[i] + ch1);
        if (pf) stageA(T + 2, spre, 1);
        __builtin_amdgcn_s_barrier();
        LGKM0();
        __builtin_amdgcn_s_setprio(1);
#pragma unroll
        for (int i = 0; i < 4; i++) {
            acc[i][2] = mfma16(a0[i], b0[2], acc[i][2]);
            acc[i][3] = mfma16(a0[i], b0[3], acc[i][3]);
        }
        __builtin_amdgcn_s_setprio(0);
        __builtin_amdgcn_s_barrier();

        // ---- phase 2: read B(k1) [4]; stage B-unit0(T+2); MFMA (k1, j=0,1)
#pragma unroll
        for (int j = 0; j < 4; j++) b1[j] = *reinterpret_cast<const bf16x8*>(bB + lbB[j] + ch1);
        if (pf) stageB(T + 2, spre, 0);
        __builtin_amdgcn_s_barrier();
        LGKM0();
        __builtin_amdgcn_s_setprio(1);
#pragma unroll
        for (int i = 0; i < 4; i++) {
            acc[i][0] = mfma16(a1[i], b1[0], acc[i][0]);
            acc[i][1] = mfma16(a1[i], b1[1], acc[i][1]);
        }
        __builtin_amdgcn_s_setprio(0);
        __builtin_amdgcn_s_barrier();

        // ---- phase 3: stage B-unit1(T+2); MFMA (k1, j=2,3); boundary wait
        if (pf) stageB(T + 2, spre, 1);
        __builtin_amdgcn_s_barrier();
        LGKM0();
        __builtin_amdgcn_s_setprio(1);
#pragma unroll
        for (int i = 0; i < 4; i++) {
            acc[i][2] = mfma16(a1[i], b1[2], acc[i][2]);
            acc[i][3] = mfma16(a1[i], b1[3], acc[i][3]);
        }
        __builtin_amdgcn_s_setprio(0);
        if (T + 1 < NT) {
            if (pf) { VMCNT(6); } else { VMCNT(0); }   // T+1 resident; 6 newest stay in flight
        }
        __builtin_amdgcn_s_barrier();
        scur = (scur == 2) ? 0 : scur + 1;
        spre = (spre == 2) ? 0 : spre + 1;
    }

    // ---------------- epilogue ----------------
    if constexpr (EPI == EPI_FPT) __syncthreads();   // LDS reuse safety

#pragma unroll
    for (int i = 0; i < 4; i++) {
        const int gr = row0 + rw0 + i * 16 + quad * 4;   // local (per-z) row
        if constexpr (EPI == EPI_FPT) {
            float qp[4] = {}, kp[4] = {};
            const int nl = rw0 + i * 16 + quad * 4;      // local row in tile (0..255)
#pragma unroll
            for (int j = 0; j < 4; j++) {
                int gc = col0 + cw0 + j * 16 + lm;
                int dl = cw0 + j * 16 + lm;              // local col in tile (0..127)
                float bias = g.e.b1[gc];
                float v0 = acc[i][j][0] + bias, v1 = acc[i][j][1] + bias;
                float v2 = acc[i][j][2] + bias, v3 = acc[i][j][3] + bias;
                us4 o; o.x = f2bf(v0); o.y = f2bf(v1); o.z = f2bf(v2); o.w = f2bf(v3);
                *reinterpret_cast<us4*>(lA + dl * 264 + nl) = o;   // LDS transpose stage
                float wqv = g.e.wq[gc], wkv = g.e.wk[gc];
                qp[0] = fmaf(v0, wqv, qp[0]); qp[1] = fmaf(v1, wqv, qp[1]);
                qp[2] = fmaf(v2, wqv, qp[2]); qp[3] = fmaf(v3, wqv, qp[3]);
                kp[0] = fmaf(v0, wkv, kp[0]); kp[1] = fmaf(v1, wkv, kp[1]);
                kp[2] = fmaf(v2, wkv, kp[2]); kp[3] = fmaf(v3, wkv, kp[3]);
            }
#pragma unroll
            for (int r = 0; r < 4; r++) {
                float q = qp[r], k = kp[r];
#pragma unroll
                for (int m = 1; m < 16; m <<= 1) { q += __shfl_xor(q, m); k += __shfl_xor(k, m); }
                if (lm == 0) { atomicAdd(g.e.qv + gr + r, q); atomicAdd(g.e.kv + gr + r, k); }
            }
        } else if constexpr (EPI == EPI_Y) {
            size_t grow = (size_t)blockIdx.z * 1024 + gr;
#pragma unroll
            for (int j = 0; j < 4; j++) {
                int gc = col0 + cw0 + j * 16 + lm;
#pragma unroll
                for (int r = 0; r < 4; r++)
                    g.e.catA[(grow + r) * 1536 + gc] = f2bf(acc[i][j][r]);
            }
        } else if constexpr (EPI == EPI_GATES) {
#pragma unroll
            for (int j = 0; j < 4; j++) {
                int gc = col0 + cw0 + j * 16 + lm;
                if (grp == 0) {
                    float bias = g.e.b1[gc] + g.e.b2[gc];      // b_uy + b_ux
#pragma unroll
                    for (int r = 0; r < 4; r++) {
                        size_t idx = (size_t)(gr + r) * 768 + gc;
                        g.e.ub_o[idx] = f2bf(1.f / (1.f + __expf(-(acc[i][j][r] + bias))));
                    }
                } else {
                    float bias = g.e.b3[gc] + g.e.b4[gc];      // b_ry + b_rx
#pragma unroll
                    for (int r = 0; r < 4; r++) {
                        size_t idx = (size_t)(gr + r) * 768 + gc;
                        float rr = 1.f / (1.f + __expf(-(acc[i][j][r] + bias)));
                        float xv = bf2f(g.e.xb[(size_t)(gr + r) * 1536 + gc]);
                        g.e.rxb_o[idx] = f2bf(rr * xv);
                    }
                }
            }
        } else {  // EPI_OUT: acc = y@Wty + rx@Wtx
#pragma unroll
            for (int j = 0; j < 4; j++) {
                int gc = col0 + cw0 + j * 16 + lm;
                float bias = g.e.b1[gc] + g.e.b2[gc];          // b_ty + b_tx
#pragma unroll
                for (int r = 0; r < 4; r++) {
                    size_t idx = (size_t)(gr + r) * 768 + gc;
                    float tv = tanhf(acc[i][j][r] + bias);
                    float uu = bf2f(g.e.ub[idx]);
                    float xv = bf2f(g.e.xb[(size_t)(gr + r) * 1536 + gc]);
                    g.e.of[idx] = (1.f - uu) * xv + uu * tv;
                }
            }
        }
    }

    // FPT: coalesced transposed store — 128 d-rows x 512B contiguous n
    if constexpr (EPI == EPI_FPT) {
        __syncthreads();
        const int bb = row0 >> 10, nn0 = row0 & 1023;   // tile spans one batch
        const int dl = t >> 2, seg = t & 3;
        const u16* src = lA + dl * 264 + seg * 64;
        u16* dst = g.e.fpT + (size_t)bb * 786432 + (size_t)(col0 + dl) * 1024 + nn0 + seg * 64;
#pragma unroll
        for (int c = 0; c < 8; c++)
            *reinterpret_cast<bf16x8*>(dst + c * 8) =
                *reinterpret_cast<const bf16x8*>(src + c * 8);
    }
}

__global__ __launch_bounds__(512, 2) void gFPT(GArgs g)   { gk_body<EPI_FPT>(g); }
__global__ __launch_bounds__(512, 2) void gY(GArgs g)     { gk_body<EPI_Y>(g); }
__global__ __launch_bounds__(512, 2) void gGATES(GArgs g) { gk_body<EPI_GATES>(g); }
__global__ __launch_bounds__(512, 2) void gOUT(GArgs g)   { gk_body<EPI_OUT>(g); }

// ---------------- softmax: one wave per row, shuffle-only reductions ----------------
__global__ __launch_bounds__(256) void k_soft4(const float* __restrict__ adj,
                                               const float* __restrict__ qv,
                                               const float* __restrict__ kv,
                                               const float* __restrict__ bq,
                                               const float* __restrict__ bk,
                                               u16* __restrict__ attb) {
    int wv = threadIdx.x >> 6, lane = threadIdx.x & 63;
    int bn = blockIdx.x * 4 + wv;
    int b = bn >> 10;
    const float* adjrow = adj + (size_t)bn * 1024 + lane * 16;
    const float* krow = kv + (b << 10) + lane * 16;
    float q = qv[bn] + bq[0] + bk[0];

    float v[16];
#pragma unroll
    for (int c = 0; c < 4; c++) {
        float4 a4 = *reinterpret_cast<const float4*>(adjrow + c * 4);
        float4 k4 = *reinterpret_cast<const float4*>(krow + c * 4);
        float* vv = v + c * 4;
        vv[0] = q + k4.x + (1.f - a4.x) * -1.0e9f;
        vv[1] = q + k4.y + (1.f - a4.y) * -1.0e9f;
        vv[2] = q + k4.z + (1.f - a4.z) * -1.0e9f;
        vv[3] = q + k4.w + (1.f - a4.w) * -1.0e9f;
    }
#pragma unroll
    for (int tt = 0; tt < 16; tt++) v[tt] = v[tt] >= 0.f ? v[tt] : 0.01f * v[tt];

    float mx = v[0];
#pragma unroll
    for (int tt = 1; tt < 16; tt++) mx = fmaxf(mx, v[tt]);
#pragma unroll
    for (int off = 32; off; off >>= 1) mx = fmaxf(mx, __shfl_xor(mx, off));

    float s = 0.f;
#pragma unroll
    for (int tt = 0; tt < 16; tt++) { v[tt] = __expf(v[tt] - mx); s += v[tt]; }
#pragma unroll
    for (int off = 32; off; off >>= 1) s += __shfl_xor(s, off);
    float inv = 1.f / s;

    u16* orow = attb + (size_t)bn * 1024 + lane * 16;
#pragma unroll
    for (int c = 0; c < 4; c++) {
        us4 o;
        o.x = f2bf(v[c * 4 + 0] * inv); o.y = f2bf(v[c * 4 + 1] * inv);
        o.z = f2bf(v[c * 4 + 2] * inv); o.w = f2bf(v[c * 4 + 3] * inv);
        *reinterpret_cast<us4*>(orow + c * 4) = o;
    }
}

extern "C" void kernel_launch(void* const* d_in, const int* in_sizes, int n_in,
                              void* d_out, int out_size, void* d_ws, size_t ws_size,
                              hipStream_t stream) {
    const float* x    = (const float*)d_in[0];
    const float* adj  = (const float*)d_in[1];
    const float* W_fc = (const float*)d_in[2];
    const float* b_fc = (const float*)d_in[3];
    const float* w_q  = (const float*)d_in[4];
    const float* b_q  = (const float*)d_in[5];
    const float* w_k  = (const float*)d_in[6];
    const float* b_k  = (const float*)d_in[7];
    const float* W_uy = (const float*)d_in[8];
    const float* b_uy = (const float*)d_in[9];
    const float* W_ux = (const float*)d_in[10];
    const float* b_ux = (const float*)d_in[11];
    const float* W_ry = (const float*)d_in[12];
    const float* b_ry = (const float*)d_in[13];
    const float* W_rx = (const float*)d_in[14];
    const float* b_rx = (const float*)d_in[15];
    const float* W_ty = (const float*)d_in[16];
    const float* b_ty = (const float*)d_in[17];
    const float* W_tx = (const float*)d_in[18];
    const float* b_tx = (const float*)d_in[19];

    char* ws = (char*)d_ws;
    u16*   CatA  = (u16*)  (ws + 0);            // 16384x1536 bf16  [y | x]   50331648
    u16*   Wfc_b = (u16*)  (ws + 50331648);     //  1179648
    u16*   Wty_b = (u16*)  (ws + 51511296);     //  1179648
    u16*   Wtx_b = (u16*)  (ws + 52690944);     //  1179648
    u16*   Wg    = (u16*)  (ws + 53870592);     // [ [Wuy|Wux] ; [Wry|Wrx] ] 4718592
    u16*   fpT   = (u16*)  (ws + 58589184);     // 16x768x1024 bf16          25165824
    float* qv    = (float*)(ws + 83755008);     // 16384 f32
    float* kv    = (float*)(ws + 83820544);     // 16384 f32
    u16*   attb  = (u16*)  (ws + 83886080);     // 16x1024x1024 bf16         33554432
    u16*   u_b   = (u16*)  (ws + 83886080);     // alias attb (dead after av)
    u16*   rxb   = (u16*)  (ws + 117440512);    // 16384x768 bf16            25165824

    cvtx<<<12288, 256, 0, stream>>>(x, CatA, qv);   // qv,kv contiguous: zeroes both

    WCvt wc;
    wc.s[0] = W_fc; wc.d[0] = Wfc_b;              wc.ld[0] = 768;
    wc.s[1] = W_ty; wc.d[1] = Wty_b;              wc.ld[1] = 768;
    wc.s[2] = W_tx; wc.d[2] = Wtx_b;              wc.ld[2] = 768;
    wc.s[3] = W_uy; wc.d[3] = Wg;                 wc.ld[3] = 1536;
    wc.s[4] = W_ux; wc.d[4] = Wg + 768;           wc.ld[4] = 1536;
    wc.s[5] = W_ry; wc.d[5] = Wg + 768 * 1536;    wc.ld[5] = 1536;
    wc.s[6] = W_rx; wc.d[6] = Wg + 768 * 1536 + 768; wc.ld[6] = 1536;
    cvtw<<<dim3(576, 7), 256, 0, stream>>>(wc);

    Epi e{};
    GArgs ga;

    // feat_proj = x @ Wfc^T + b (A = CatA right half), + fused q/k partials
    e = Epi{}; e.b1 = b_fc; e.wq = w_q; e.wk = w_k; e.qv = qv; e.kv = kv; e.fpT = fpT;
    ga = GArgs{CatA + 768, Wfc_b, nullptr, nullptr, 12, 0, 1536, 768, 0, 0, 0, 0, e};
    gFPT<<<dim3(64, 6), 512, 0, stream>>>(ga);

    k_soft4<<<4096, 256, 0, stream>>>(adj, qv, kv, b_q, b_k, attb);

    // y = att @ fp  -> CatA left half
    e = Epi{}; e.catA = CatA;
    ga = GArgs{attb, fpT, nullptr, nullptr, 16, 0, 1024, 1024, 0, 0, 1048576, 786432, e};
    gY<<<dim3(4, 6, 16), 512, 0, stream>>>(ga);

    // gates: [u | r] = CatA @ [Wuy|Wux ; Wry|Wrx]^T
    e = Epi{}; e.b1 = b_uy; e.b2 = b_ux; e.b3 = b_ry; e.b4 = b_rx;
    e.xb = CatA + 768; e.ub_o = u_b; e.rxb_o = rxb;
    ga = GArgs{CatA, Wg, nullptr, nullptr, 24, 0, 1536, 1536, 0, 0, 0, 0, e};
    gGATES<<<dim3(64, 12), 512, 0, stream>>>(ga);

    // out = (1-u)x + u*tanh(y@Wty^T + rx@Wtx^T + b_ty + b_tx)
    e = Epi{}; e.b1 = b_ty; e.b2 = b_tx; e.ub = u_b; e.xb = CatA + 768; e.of = (float*)d_out;
    ga = GArgs{CatA, Wty_b, rxb, Wtx_b, 12, 12, 1536, 768, 768, 768, 0, 0, e};
    gOUT<<<dim3(64, 6), 512, 0, stream>>>(ga);
}

// Round 5
// 422.492 us; speedup vs baseline: 1.2743x; 1.2743x over previous
//
#include <hip/hip_runtime.h>
#include <cmath>

typedef __attribute__((ext_vector_type(8))) short bf16x8;
typedef __attribute__((ext_vector_type(4))) float f32x4;
typedef unsigned short u16;

struct __align__(8) us4 { u16 x, y, z, w; };

__device__ __forceinline__ u16 f2bf(float f) {
    union { float f; unsigned u; } v; v.f = f;
    unsigned u = v.u;
    u += 0x7fffu + ((u >> 16) & 1u);   // RNE
    return (u16)(u >> 16);
}
__device__ __forceinline__ float bf2f(u16 h) {
    union { unsigned u; float f; } v; v.u = ((unsigned)h) << 16;
    return v.f;
}
__device__ __forceinline__ float fast_tanh(float x) {
    // tanh(x) = sign(x) * (1 - t)/(1 + t), t = exp(-2|x|)  (t in (0,1]; no inf path)
    float t = __expf(-2.f * fabsf(x));
    float th = (1.f - t) / (1.f + t);
    return copysignf(th, x);
}
__device__ __forceinline__ f32x4 mfma16(bf16x8 a, bf16x8 b, f32x4 c) {
    return __builtin_amdgcn_mfma_f32_16x16x32_bf16(a, b, c, 0, 0, 0);
}
__device__ __forceinline__ void ld_lds16(const u16* g, u16* l) {
    __builtin_amdgcn_global_load_lds(
        (const __attribute__((address_space(1))) unsigned int*)g,
        (__attribute__((address_space(3))) unsigned int*)l, 16, 0, 0);
}

// ---------------- x -> CatA right half (bf16) + zero qv/kv ----------------
__global__ __launch_bounds__(256) void cvtx(const float* __restrict__ in,
                                            u16* __restrict__ CatA, float* __restrict__ qkz) {
    int i = blockIdx.x * 256 + threadIdx.x;         // over 3145728 float4 groups
    float4 f = reinterpret_cast<const float4*>(in)[i];
    us4 o; o.x = f2bf(f.x); o.y = f2bf(f.y); o.z = f2bf(f.z); o.w = f2bf(f.w);
    int row = i / 192, col = (i % 192) * 4;
    *reinterpret_cast<us4*>(CatA + (size_t)row * 1536 + 768 + col) = o;
    if (i < 8192) reinterpret_cast<float4*>(qkz)[i] = float4{0.f, 0.f, 0.f, 0.f};
}

// ---------------- 7 weight converts in one dispatch ----------------
struct WCvt { const float* s[7]; u16* d[7]; int ld[7]; };
__global__ __launch_bounds__(256) void cvtw(WCvt w) {
    int wi = blockIdx.y;
    int i = blockIdx.x * 256 + threadIdx.x;         // over 147456 float4 groups
    float4 f = reinterpret_cast<const float4*>(w.s[wi])[i];
    us4 o; o.x = f2bf(f.x); o.y = f2bf(f.y); o.z = f2bf(f.z); o.w = f2bf(f.w);
    int row = i / 192, col = (i % 192) * 4;
    *reinterpret_cast<us4*>(w.d[wi] + (size_t)row * w.ld[wi] + col) = o;
}

// =====================================================================
// m97-style GEMM, 128x128 tile, BK=64 — EXACT round-0 main loop
// (measured best: total 438us, GATES 102.8us, MfmaUtil 32%, 0 bank
// conflicts, ~2.3 blk/CU inter-block overlap). Frozen after three
// deep-pipeline attempts regressed (r1 -26%, r2 -9%, r4 -39%).
// This round: per-EPI kernel names for rocprof attribution + fast
// expf-based tanh in the OUT epilogue (was libm tanhf x 12.6M).
// =====================================================================
enum { EPI_FPT = 0, EPI_Y, EPI_GATES, EPI_OUT };

struct Epi {
    const float* b1; const float* b2; const float* b3; const float* b4;
    const float* wq; const float* wk; float* qv; float* kv;   // FPT
    u16* fpT;
    u16* catA;                                                 // Y
    const u16* xb;        // CatA+768 (stride 1536)
    u16* ub_o; u16* rxb_o;                                     // GATES
    const u16* ub; float* of;                                  // OUT
};

template<int EPI, int PH>
__device__ __forceinline__ void g128_body(
    const u16* __restrict__ A1, const u16* __restrict__ B1,
    const u16* __restrict__ A2, const u16* __restrict__ B2,
    int K, int ldA1, int ldB1, int ldA2, int ldB2,
    size_t zA, size_t zB, Epi e)
{
    __shared__ u16 lA[128 * 64];
    __shared__ u16 lB[128 * 64];

    const int t = threadIdx.x;
    const int w = t >> 6, lane = t & 63, lm = lane & 15, quad = lane >> 4;
    const int row0 = blockIdx.x * 128;
    int col0, grp = 0;
    if constexpr (EPI == EPI_GATES) { grp = blockIdx.y / 6; col0 = (blockIdx.y % 6) * 128; }
    else col0 = blockIdx.y * 128;

    // staging: linear chunk-id n = q*256 + t; LDS offset = n*16B (fits
    // wave-uniform base + lane*16). Global: row = row0 + q*32 + (t>>3),
    // chunk = (t&7) ^ ((t>>3)&7)  [XOR swizzle vs row&7].
    const int rs2 = t >> 3;                         // 0..31
    const int kc2 = (((t & 7) ^ (rs2 & 7)) * 8);
    u16* dA_[4]; u16* dB_[4];
#pragma unroll
    for (int q = 0; q < 4; q++) {
        dA_[q] = lA + q * 2048 + w * 512;
        dB_[q] = lB + q * 2048 + w * 512;
    }

    // compute map: wave (w&1) row-half, (w>>1) col-half
    const int rw0 = (w & 1) * 64, cw0 = (w >> 1) * 64;
    // LDS read: row R, logical k-half h chunk (quad+4h); stored at chunk^( R&7 ), R&7 == lm&7
    const int ch0 = ((quad) ^ (lm & 7)) * 8;
    const int ch1 = ((quad + 4) ^ (lm & 7)) * 8;
    int laB[4], lbB[4];
#pragma unroll
    for (int i = 0; i < 4; i++) laB[i] = (rw0 + i * 16 + lm) * 64;
#pragma unroll
    for (int j = 0; j < 4; j++) lbB[j] = (cw0 + j * 16 + lm) * 64;

    f32x4 acc[4][4] = {};
    bool first = true;

#pragma unroll
    for (int ph = 0; ph < PH; ph++) {
        const u16* As; const u16* Bs; int ldA, ldB;
        if (ph == 0) { As = A1 + (size_t)blockIdx.z * zA; Bs = B1 + (size_t)blockIdx.z * zB; ldA = ldA1; ldB = ldB1; }
        else         { As = A2; Bs = B2; ldA = ldA2; ldB = ldB2; }
        if constexpr (EPI == EPI_GATES) Bs += (size_t)grp * (768 * 1536);
        const u16* gA = As + (size_t)(row0 + rs2) * ldA + kc2;
        const u16* gB = Bs + (size_t)(col0 + rs2) * ldB + kc2;

        for (int k0 = 0; k0 < K; k0 += 64) {
            if (!first) __syncthreads();
            first = false;
#pragma unroll
            for (int q = 0; q < 4; q++) {
                ld_lds16(gA + (size_t)(q * 32) * ldA + k0, dA_[q]);
                ld_lds16(gB + (size_t)(q * 32) * ldB + k0, dB_[q]);
            }
            __syncthreads();

#pragma unroll
            for (int h = 0; h < 2; h++) {
                const int ch = h ? ch1 : ch0;
                bf16x8 a[4], b[4];
#pragma unroll
                for (int i = 0; i < 4; i++) a[i] = *reinterpret_cast<const bf16x8*>(lA + laB[i] + ch);
#pragma unroll
                for (int j = 0; j < 4; j++) b[j] = *reinterpret_cast<const bf16x8*>(lB + lbB[j] + ch);
#pragma unroll
                for (int i = 0; i < 4; i++)
#pragma unroll
                    for (int j = 0; j < 4; j++)
                        acc[i][j] = mfma16(a[i], b[j], acc[i][j]);
            }
        }
    }

    // ---------------- epilogue ----------------
#pragma unroll
    for (int i = 0; i < 4; i++) {
        const int gr = row0 + rw0 + i * 16 + quad * 4;   // local (per-z) row
        if constexpr (EPI == EPI_FPT) {
            float qp[4] = {}, kp[4] = {};
            int bb = gr >> 10, nn = gr & 1023;
#pragma unroll
            for (int j = 0; j < 4; j++) {
                int gc = col0 + cw0 + j * 16 + lm;
                float bias = e.b1[gc];
                float v0 = acc[i][j][0] + bias, v1 = acc[i][j][1] + bias;
                float v2 = acc[i][j][2] + bias, v3 = acc[i][j][3] + bias;
                us4 o; o.x = f2bf(v0); o.y = f2bf(v1); o.z = f2bf(v2); o.w = f2bf(v3);
                *reinterpret_cast<us4*>(e.fpT + (size_t)bb * 786432 + (size_t)gc * 1024 + nn) = o;
                float wqv = e.wq[gc], wkv = e.wk[gc];
                qp[0] = fmaf(v0, wqv, qp[0]); qp[1] = fmaf(v1, wqv, qp[1]);
                qp[2] = fmaf(v2, wqv, qp[2]); qp[3] = fmaf(v3, wqv, qp[3]);
                kp[0] = fmaf(v0, wkv, kp[0]); kp[1] = fmaf(v1, wkv, kp[1]);
                kp[2] = fmaf(v2, wkv, kp[2]); kp[3] = fmaf(v3, wkv, kp[3]);
            }
#pragma unroll
            for (int r = 0; r < 4; r++) {
                float q = qp[r], k = kp[r];
#pragma unroll
                for (int m = 1; m < 16; m <<= 1) { q += __shfl_xor(q, m); k += __shfl_xor(k, m); }
                if (lm == 0) { atomicAdd(e.qv + gr + r, q); atomicAdd(e.kv + gr + r, k); }
            }
        } else if constexpr (EPI == EPI_Y) {
            size_t grow = (size_t)blockIdx.z * 1024 + gr;
#pragma unroll
            for (int j = 0; j < 4; j++) {
                int gc = col0 + cw0 + j * 16 + lm;
#pragma unroll
                for (int r = 0; r < 4; r++)
                    e.catA[(grow + r) * 1536 + gc] = f2bf(acc[i][j][r]);
            }
        } else if constexpr (EPI == EPI_GATES) {
#pragma unroll
            for (int j = 0; j < 4; j++) {
                int gc = col0 + cw0 + j * 16 + lm;
                if (grp == 0) {
                    float bias = e.b1[gc] + e.b2[gc];      // b_uy + b_ux
#pragma unroll
                    for (int r = 0; r < 4; r++) {
                        size_t idx = (size_t)(gr + r) * 768 + gc;
                        e.ub_o[idx] = f2bf(1.f / (1.f + __expf(-(acc[i][j][r] + bias))));
                    }
                } else {
                    float bias = e.b3[gc] + e.b4[gc];      // b_ry + b_rx
#pragma unroll
                    for (int r = 0; r < 4; r++) {
                        size_t idx = (size_t)(gr + r) * 768 + gc;
                        float rr = 1.f / (1.f + __expf(-(acc[i][j][r] + bias)));
                        float xv = bf2f(e.xb[(size_t)(gr + r) * 1536 + gc]);
                        e.rxb_o[idx] = f2bf(rr * xv);
                    }
                }
            }
        } else {  // EPI_OUT: acc = y@Wty + rx@Wtx
#pragma unroll
            for (int j = 0; j < 4; j++) {
                int gc = col0 + cw0 + j * 16 + lm;
                float bias = e.b1[gc] + e.b2[gc];          // b_ty + b_tx
#pragma unroll
                for (int r = 0; r < 4; r++) {
                    size_t idx = (size_t)(gr + r) * 768 + gc;
                    float tt = fast_tanh(acc[i][j][r] + bias);
                    float uu = bf2f(e.ub[idx]);
                    float xv = bf2f(e.xb[(size_t)(gr + r) * 1536 + gc]);
                    e.of[idx] = (1.f - uu) * xv + uu * tt;
                }
            }
        }
    }
}

// per-EPI symbols for rocprof attribution
__global__ __launch_bounds__(256) void gFPT(
    const u16* __restrict__ A1, const u16* __restrict__ B1, int K, int ldA1, int ldB1, Epi e) {
    g128_body<EPI_FPT, 1>(A1, B1, nullptr, nullptr, K, ldA1, ldB1, 0, 0, 0, 0, e);
}
__global__ __launch_bounds__(256) void gY(
    const u16* __restrict__ A1, const u16* __restrict__ B1, int K, int ldA1, int ldB1,
    size_t zA, size_t zB, Epi e) {
    g128_body<EPI_Y, 1>(A1, B1, nullptr, nullptr, K, ldA1, ldB1, 0, 0, zA, zB, e);
}
__global__ __launch_bounds__(256) void gGATES(
    const u16* __restrict__ A1, const u16* __restrict__ B1, int K, int ldA1, int ldB1, Epi e) {
    g128_body<EPI_GATES, 1>(A1, B1, nullptr, nullptr, K, ldA1, ldB1, 0, 0, 0, 0, e);
}
__global__ __launch_bounds__(256) void gOUT(
    const u16* __restrict__ A1, const u16* __restrict__ B1,
    const u16* __restrict__ A2, const u16* __restrict__ B2,
    int K, int ldA1, int ldB1, int ldA2, int ldB2, Epi e) {
    g128_body<EPI_OUT, 2>(A1, B1, A2, B2, K, ldA1, ldB1, ldA2, ldB2, 0, 0, e);
}

// ---------------- softmax: one wave per row, shuffle-only reductions ----------------
__global__ __launch_bounds__(256) void k_soft4(const float* __restrict__ adj,
                                               const float* __restrict__ qv,
                                               const float* __restrict__ kv,
                                               const float* __restrict__ bq,
                                               const float* __restrict__ bk,
                                               u16* __restrict__ attb) {
    int wv = threadIdx.x >> 6, lane = threadIdx.x & 63;
    int bn = blockIdx.x * 4 + wv;
    int b = bn >> 10;
    const float* adjrow = adj + (size_t)bn * 1024 + lane * 16;
    const float* krow = kv + (b << 10) + lane * 16;
    float q = qv[bn] + bq[0] + bk[0];

    float v[16];
#pragma unroll
    for (int c = 0; c < 4; c++) {
        float4 a4 = *reinterpret_cast<const float4*>(adjrow + c * 4);
        float4 k4 = *reinterpret_cast<const float4*>(krow + c * 4);
        float* vv = v + c * 4;
        vv[0] = q + k4.x + (1.f - a4.x) * -1.0e9f;
        vv[1] = q + k4.y + (1.f - a4.y) * -1.0e9f;
        vv[2] = q + k4.z + (1.f - a4.z) * -1.0e9f;
        vv[3] = q + k4.w + (1.f - a4.w) * -1.0e9f;
    }
#pragma unroll
    for (int t = 0; t < 16; t++) v[t] = v[t] >= 0.f ? v[t] : 0.01f * v[t];

    float mx = v[0];
#pragma unroll
    for (int t = 1; t < 16; t++) mx = fmaxf(mx, v[t]);
#pragma unroll
    for (int off = 32; off; off >>= 1) mx = fmaxf(mx, __shfl_xor(mx, off));

    float s = 0.f;
#pragma unroll
    for (int t = 0; t < 16; t++) { v[t] = __expf(v[t] - mx); s += v[t]; }
#pragma unroll
    for (int off = 32; off; off >>= 1) s += __shfl_xor(s, off);
    float inv = 1.f / s;

    u16* orow = attb + (size_t)bn * 1024 + lane * 16;
#pragma unroll
    for (int c = 0; c < 4; c++) {
        us4 o;
        o.x = f2bf(v[c * 4 + 0] * inv); o.y = f2bf(v[c * 4 + 1] * inv);
        o.z = f2bf(v[c * 4 + 2] * inv); o.w = f2bf(v[c * 4 + 3] * inv);
        *reinterpret_cast<us4*>(orow + c * 4) = o;
    }
}

extern "C" void kernel_launch(void* const* d_in, const int* in_sizes, int n_in,
                              void* d_out, int out_size, void* d_ws, size_t ws_size,
                              hipStream_t stream) {
    const float* x    = (const float*)d_in[0];
    const float* adj  = (const float*)d_in[1];
    const float* W_fc = (const float*)d_in[2];
    const float* b_fc = (const float*)d_in[3];
    const float* w_q  = (const float*)d_in[4];
    const float* b_q  = (const float*)d_in[5];
    const float* w_k  = (const float*)d_in[6];
    const float* b_k  = (const float*)d_in[7];
    const float* W_uy = (const float*)d_in[8];
    const float* b_uy = (const float*)d_in[9];
    const float* W_ux = (const float*)d_in[10];
    const float* b_ux = (const float*)d_in[11];
    const float* W_ry = (const float*)d_in[12];
    const float* b_ry = (const float*)d_in[13];
    const float* W_rx = (const float*)d_in[14];
    const float* b_rx = (const float*)d_in[15];
    const float* W_ty = (const float*)d_in[16];
    const float* b_ty = (const float*)d_in[17];
    const float* W_tx = (const float*)d_in[18];
    const float* b_tx = (const float*)d_in[19];

    char* ws = (char*)d_ws;
    u16*   CatA  = (u16*)  (ws + 0);            // 16384x1536 bf16  [y | x]   50331648
    u16*   Wfc_b = (u16*)  (ws + 50331648);     //  1179648
    u16*   Wty_b = (u16*)  (ws + 51511296);     //  1179648
    u16*   Wtx_b = (u16*)  (ws + 52690944);     //  1179648
    u16*   Wg    = (u16*)  (ws + 53870592);     // [ [Wuy|Wux] ; [Wry|Wrx] ] 4718592
    u16*   fpT   = (u16*)  (ws + 58589184);     // 16x768x1024 bf16          25165824
    float* qv    = (float*)(ws + 83755008);     // 16384 f32
    float* kv    = (float*)(ws + 83820544);     // 16384 f32
    u16*   attb  = (u16*)  (ws + 83886080);     // 16x1024x1024 bf16         33554432
    u16*   u_b   = (u16*)  (ws + 83886080);     // alias attb (dead after av)
    u16*   rxb   = (u16*)  (ws + 117440512);    // 16384x768 bf16            25165824

    cvtx<<<12288, 256, 0, stream>>>(x, CatA, qv);   // qv,kv contiguous: zeroes both

    WCvt wc;
    wc.s[0] = W_fc; wc.d[0] = Wfc_b;              wc.ld[0] = 768;
    wc.s[1] = W_ty; wc.d[1] = Wty_b;              wc.ld[1] = 768;
    wc.s[2] = W_tx; wc.d[2] = Wtx_b;              wc.ld[2] = 768;
    wc.s[3] = W_uy; wc.d[3] = Wg;                 wc.ld[3] = 1536;
    wc.s[4] = W_ux; wc.d[4] = Wg + 768;           wc.ld[4] = 1536;
    wc.s[5] = W_ry; wc.d[5] = Wg + 768 * 1536;    wc.ld[5] = 1536;
    wc.s[6] = W_rx; wc.d[6] = Wg + 768 * 1536 + 768; wc.ld[6] = 1536;
    cvtw<<<dim3(576, 7), 256, 0, stream>>>(wc);

    Epi e{};
    // feat_proj = x @ Wfc^T + b (A = CatA right half), + fused q/k partials
    e = Epi{}; e.b1 = b_fc; e.wq = w_q; e.wk = w_k; e.qv = qv; e.kv = kv; e.fpT = fpT;
    gFPT<<<dim3(128, 6), 256, 0, stream>>>(CatA + 768, Wfc_b, 768, 1536, 768, e);

    k_soft4<<<4096, 256, 0, stream>>>(adj, qv, kv, b_q, b_k, attb);

    // y = att @ fp  -> CatA left half
    e = Epi{}; e.catA = CatA;
    gY<<<dim3(8, 6, 16), 256, 0, stream>>>(attb, fpT, 1024, 1024, 1024,
                                           1048576, 786432, e);
    // gates: [u | r] = CatA @ [Wuy|Wux ; Wry|Wrx]^T
    e = Epi{}; e.b1 = b_uy; e.b2 = b_ux; e.b3 = b_ry; e.b4 = b_rx;
    e.xb = CatA + 768; e.ub_o = u_b; e.rxb_o = rxb;
    gGATES<<<dim3(128, 12), 256, 0, stream>>>(CatA, Wg, 1536, 1536, 1536, e);

    // out = (1-u)x + u*tanh(y@Wty^T + rx@Wtx^T + b_ty + b_tx)
    e = Epi{}; e.b1 = b_ty; e.b2 = b_tx; e.ub = u_b; e.xb = CatA + 768; e.of = (float*)d_out;
    gOUT<<<dim3(128, 6), 256, 0, stream>>>(CatA, Wty_b, rxb, Wtx_b,
                                           768, 1536, 768, 768, 768, e);
}

// Round 6
// 419.127 us; speedup vs baseline: 1.2846x; 1.0080x over previous
//
#include <hip/hip_runtime.h>
#include <cmath>

typedef __attribute__((ext_vector_type(8))) short bf16x8;
typedef __attribute__((ext_vector_type(4))) float f32x4;
typedef unsigned short u16;

struct __align__(8) us4 { u16 x, y, z, w; };

__device__ __forceinline__ u16 f2bf(float f) {
    union { float f; unsigned u; } v; v.f = f;
    unsigned u = v.u;
    u += 0x7fffu + ((u >> 16) & 1u);   // RNE
    return (u16)(u >> 16);
}
__device__ __forceinline__ float bf2f(u16 h) {
    union { unsigned u; float f; } v; v.u = ((unsigned)h) << 16;
    return v.f;
}
__device__ __forceinline__ float fast_tanh(float x) {
    // tanh(x) = sign(x) * (1 - t)/(1 + t), t = exp(-2|x|)  (t in (0,1]; no inf path)
    float t = __expf(-2.f * fabsf(x));
    float th = (1.f - t) / (1.f + t);
    return copysignf(th, x);
}
__device__ __forceinline__ f32x4 mfma16(bf16x8 a, bf16x8 b, f32x4 c) {
    return __builtin_amdgcn_mfma_f32_16x16x32_bf16(a, b, c, 0, 0, 0);
}
__device__ __forceinline__ void ld_lds16(const u16* g, u16* l) {
    __builtin_amdgcn_global_load_lds(
        (const __attribute__((address_space(1))) unsigned int*)g,
        (__attribute__((address_space(3))) unsigned int*)l, 16, 0, 0);
}

// ---------------- x -> CatA right half (bf16) + zero qv/kv ----------------
__global__ __launch_bounds__(256) void cvtx(const float* __restrict__ in,
                                            u16* __restrict__ CatA, float* __restrict__ qkz) {
    int i = blockIdx.x * 256 + threadIdx.x;         // over 3145728 float4 groups
    float4 f = reinterpret_cast<const float4*>(in)[i];
    us4 o; o.x = f2bf(f.x); o.y = f2bf(f.y); o.z = f2bf(f.z); o.w = f2bf(f.w);
    int row = i / 192, col = (i % 192) * 4;
    *reinterpret_cast<us4*>(CatA + (size_t)row * 1536 + 768 + col) = o;
    if (i < 8192) reinterpret_cast<float4*>(qkz)[i] = float4{0.f, 0.f, 0.f, 0.f};
}

// ---------------- 7 weight converts in one dispatch ----------------
struct WCvt { const float* s[7]; u16* d[7]; int ld[7]; };
__global__ __launch_bounds__(256) void cvtw(WCvt w) {
    int wi = blockIdx.y;
    int i = blockIdx.x * 256 + threadIdx.x;         // over 147456 float4 groups
    float4 f = reinterpret_cast<const float4*>(w.s[wi])[i];
    us4 o; o.x = f2bf(f.x); o.y = f2bf(f.y); o.z = f2bf(f.z); o.w = f2bf(f.w);
    int row = i / 192, col = (i % 192) * 4;
    *reinterpret_cast<us4*>(w.d[wi] + (size_t)row * w.ld[wi] + col) = o;
}

// =====================================================================
// m97-style GEMM, 128x128 tile, BK=64 — frozen round-0 main loop
// (measured: total 422us, GATES 103.5us, MfmaUtil 32%, 0 bank
// conflicts, ~2.3 blk/CU inter-block overlap). Deep-pipeline attempts
// regressed 3x (r1 -26%, r2 -9%, r4 -39%) — do not touch the K-loop.
// Round 6: k_soft4 load/store coalescing (lane-major -> c-major
// element ownership; was 64 lines/instr at stride 64B on 100MB of
// traffic) + nontemporal store for the final out tensor.
// =====================================================================
enum { EPI_FPT = 0, EPI_Y, EPI_GATES, EPI_OUT };

struct Epi {
    const float* b1; const float* b2; const float* b3; const float* b4;
    const float* wq; const float* wk; float* qv; float* kv;   // FPT
    u16* fpT;
    u16* catA;                                                 // Y
    const u16* xb;        // CatA+768 (stride 1536)
    u16* ub_o; u16* rxb_o;                                     // GATES
    const u16* ub; float* of;                                  // OUT
};

template<int EPI, int PH>
__device__ __forceinline__ void g128_body(
    const u16* __restrict__ A1, const u16* __restrict__ B1,
    const u16* __restrict__ A2, const u16* __restrict__ B2,
    int K, int ldA1, int ldB1, int ldA2, int ldB2,
    size_t zA, size_t zB, Epi e)
{
    __shared__ u16 lA[128 * 64];
    __shared__ u16 lB[128 * 64];

    const int t = threadIdx.x;
    const int w = t >> 6, lane = t & 63, lm = lane & 15, quad = lane >> 4;
    const int row0 = blockIdx.x * 128;
    int col0, grp = 0;
    if constexpr (EPI == EPI_GATES) { grp = blockIdx.y / 6; col0 = (blockIdx.y % 6) * 128; }
    else col0 = blockIdx.y * 128;

    // staging: linear chunk-id n = q*256 + t; LDS offset = n*16B (fits
    // wave-uniform base + lane*16). Global: row = row0 + q*32 + (t>>3),
    // chunk = (t&7) ^ ((t>>3)&7)  [XOR swizzle vs row&7].
    const int rs2 = t >> 3;                         // 0..31
    const int kc2 = (((t & 7) ^ (rs2 & 7)) * 8);
    u16* dA_[4]; u16* dB_[4];
#pragma unroll
    for (int q = 0; q < 4; q++) {
        dA_[q] = lA + q * 2048 + w * 512;
        dB_[q] = lB + q * 2048 + w * 512;
    }

    // compute map: wave (w&1) row-half, (w>>1) col-half
    const int rw0 = (w & 1) * 64, cw0 = (w >> 1) * 64;
    // LDS read: row R, logical k-half h chunk (quad+4h); stored at chunk^( R&7 ), R&7 == lm&7
    const int ch0 = ((quad) ^ (lm & 7)) * 8;
    const int ch1 = ((quad + 4) ^ (lm & 7)) * 8;
    int laB[4], lbB[4];
#pragma unroll
    for (int i = 0; i < 4; i++) laB[i] = (rw0 + i * 16 + lm) * 64;
#pragma unroll
    for (int j = 0; j < 4; j++) lbB[j] = (cw0 + j * 16 + lm) * 64;

    f32x4 acc[4][4] = {};
    bool first = true;

#pragma unroll
    for (int ph = 0; ph < PH; ph++) {
        const u16* As; const u16* Bs; int ldA, ldB;
        if (ph == 0) { As = A1 + (size_t)blockIdx.z * zA; Bs = B1 + (size_t)blockIdx.z * zB; ldA = ldA1; ldB = ldB1; }
        else         { As = A2; Bs = B2; ldA = ldA2; ldB = ldB2; }
        if constexpr (EPI == EPI_GATES) Bs += (size_t)grp * (768 * 1536);
        const u16* gA = As + (size_t)(row0 + rs2) * ldA + kc2;
        const u16* gB = Bs + (size_t)(col0 + rs2) * ldB + kc2;

        for (int k0 = 0; k0 < K; k0 += 64) {
            if (!first) __syncthreads();
            first = false;
#pragma unroll
            for (int q = 0; q < 4; q++) {
                ld_lds16(gA + (size_t)(q * 32) * ldA + k0, dA_[q]);
                ld_lds16(gB + (size_t)(q * 32) * ldB + k0, dB_[q]);
            }
            __syncthreads();

#pragma unroll
            for (int h = 0; h < 2; h++) {
                const int ch = h ? ch1 : ch0;
                bf16x8 a[4], b[4];
#pragma unroll
                for (int i = 0; i < 4; i++) a[i] = *reinterpret_cast<const bf16x8*>(lA + laB[i] + ch);
#pragma unroll
                for (int j = 0; j < 4; j++) b[j] = *reinterpret_cast<const bf16x8*>(lB + lbB[j] + ch);
#pragma unroll
                for (int i = 0; i < 4; i++)
#pragma unroll
                    for (int j = 0; j < 4; j++)
                        acc[i][j] = mfma16(a[i], b[j], acc[i][j]);
            }
        }
    }

    // ---------------- epilogue ----------------
#pragma unroll
    for (int i = 0; i < 4; i++) {
        const int gr = row0 + rw0 + i * 16 + quad * 4;   // local (per-z) row
        if constexpr (EPI == EPI_FPT) {
            float qp[4] = {}, kp[4] = {};
            int bb = gr >> 10, nn = gr & 1023;
#pragma unroll
            for (int j = 0; j < 4; j++) {
                int gc = col0 + cw0 + j * 16 + lm;
                float bias = e.b1[gc];
                float v0 = acc[i][j][0] + bias, v1 = acc[i][j][1] + bias;
                float v2 = acc[i][j][2] + bias, v3 = acc[i][j][3] + bias;
                us4 o; o.x = f2bf(v0); o.y = f2bf(v1); o.z = f2bf(v2); o.w = f2bf(v3);
                *reinterpret_cast<us4*>(e.fpT + (size_t)bb * 786432 + (size_t)gc * 1024 + nn) = o;
                float wqv = e.wq[gc], wkv = e.wk[gc];
                qp[0] = fmaf(v0, wqv, qp[0]); qp[1] = fmaf(v1, wqv, qp[1]);
                qp[2] = fmaf(v2, wqv, qp[2]); qp[3] = fmaf(v3, wqv, qp[3]);
                kp[0] = fmaf(v0, wkv, kp[0]); kp[1] = fmaf(v1, wkv, kp[1]);
                kp[2] = fmaf(v2, wkv, kp[2]); kp[3] = fmaf(v3, wkv, kp[3]);
            }
#pragma unroll
            for (int r = 0; r < 4; r++) {
                float q = qp[r], k = kp[r];
#pragma unroll
                for (int m = 1; m < 16; m <<= 1) { q += __shfl_xor(q, m); k += __shfl_xor(k, m); }
                if (lm == 0) { atomicAdd(e.qv + gr + r, q); atomicAdd(e.kv + gr + r, k); }
            }
        } else if constexpr (EPI == EPI_Y) {
            size_t grow = (size_t)blockIdx.z * 1024 + gr;
#pragma unroll
            for (int j = 0; j < 4; j++) {
                int gc = col0 + cw0 + j * 16 + lm;
#pragma unroll
                for (int r = 0; r < 4; r++)
                    e.catA[(grow + r) * 1536 + gc] = f2bf(acc[i][j][r]);
            }
        } else if constexpr (EPI == EPI_GATES) {
#pragma unroll
            for (int j = 0; j < 4; j++) {
                int gc = col0 + cw0 + j * 16 + lm;
                if (grp == 0) {
                    float bias = e.b1[gc] + e.b2[gc];      // b_uy + b_ux
#pragma unroll
                    for (int r = 0; r < 4; r++) {
                        size_t idx = (size_t)(gr + r) * 768 + gc;
                        e.ub_o[idx] = f2bf(1.f / (1.f + __expf(-(acc[i][j][r] + bias))));
                    }
                } else {
                    float bias = e.b3[gc] + e.b4[gc];      // b_ry + b_rx
#pragma unroll
                    for (int r = 0; r < 4; r++) {
                        size_t idx = (size_t)(gr + r) * 768 + gc;
                        float rr = 1.f / (1.f + __expf(-(acc[i][j][r] + bias)));
                        float xv = bf2f(e.xb[(size_t)(gr + r) * 1536 + gc]);
                        e.rxb_o[idx] = f2bf(rr * xv);
                    }
                }
            }
        } else {  // EPI_OUT: acc = y@Wty + rx@Wtx
#pragma unroll
            for (int j = 0; j < 4; j++) {
                int gc = col0 + cw0 + j * 16 + lm;
                float bias = e.b1[gc] + e.b2[gc];          // b_ty + b_tx
#pragma unroll
                for (int r = 0; r < 4; r++) {
                    size_t idx = (size_t)(gr + r) * 768 + gc;
                    float tt = fast_tanh(acc[i][j][r] + bias);
                    float uu = bf2f(e.ub[idx]);
                    float xv = bf2f(e.xb[(size_t)(gr + r) * 1536 + gc]);
                    __builtin_nontemporal_store((1.f - uu) * xv + uu * tt, e.of + idx);
                }
            }
        }
    }
}

// per-EPI symbols for rocprof attribution
__global__ __launch_bounds__(256) void gFPT(
    const u16* __restrict__ A1, const u16* __restrict__ B1, int K, int ldA1, int ldB1, Epi e) {
    g128_body<EPI_FPT, 1>(A1, B1, nullptr, nullptr, K, ldA1, ldB1, 0, 0, 0, 0, e);
}
__global__ __launch_bounds__(256) void gY(
    const u16* __restrict__ A1, const u16* __restrict__ B1, int K, int ldA1, int ldB1,
    size_t zA, size_t zB, Epi e) {
    g128_body<EPI_Y, 1>(A1, B1, nullptr, nullptr, K, ldA1, ldB1, 0, 0, zA, zB, e);
}
__global__ __launch_bounds__(256) void gGATES(
    const u16* __restrict__ A1, const u16* __restrict__ B1, int K, int ldA1, int ldB1, Epi e) {
    g128_body<EPI_GATES, 1>(A1, B1, nullptr, nullptr, K, ldA1, ldB1, 0, 0, 0, 0, e);
}
__global__ __launch_bounds__(256) void gOUT(
    const u16* __restrict__ A1, const u16* __restrict__ B1,
    const u16* __restrict__ A2, const u16* __restrict__ B2,
    int K, int ldA1, int ldB1, int ldA2, int ldB2, Epi e) {
    g128_body<EPI_OUT, 2>(A1, B1, A2, B2, K, ldA1, ldB1, ldA2, ldB2, 0, 0, e);
}

// ---------------- softmax: one wave per row, coalesced c-major layout ----------------
// lane owns elements {c*256 + lane*4 .. +3}: every load/store instruction
// covers a contiguous 1KB (f32) / 512B (bf16) span. Reductions are
// permutation-invariant over the row.
__global__ __launch_bounds__(256) void k_soft4(const float* __restrict__ adj,
                                               const float* __restrict__ qv,
                                               const float* __restrict__ kv,
                                               const float* __restrict__ bq,
                                               const float* __restrict__ bk,
                                               u16* __restrict__ attb) {
    int wv = threadIdx.x >> 6, lane = threadIdx.x & 63;
    int bn = blockIdx.x * 4 + wv;
    int b = bn >> 10;
    const float* adjrow = adj + (size_t)bn * 1024;
    const float* krow = kv + (b << 10);
    float q = qv[bn] + bq[0] + bk[0];

    float v[16];
#pragma unroll
    for (int c = 0; c < 4; c++) {
        float4 a4 = *reinterpret_cast<const float4*>(adjrow + c * 256 + lane * 4);
        float4 k4 = *reinterpret_cast<const float4*>(krow + c * 256 + lane * 4);
        float* vv = v + c * 4;
        vv[0] = q + k4.x + (1.f - a4.x) * -1.0e9f;
        vv[1] = q + k4.y + (1.f - a4.y) * -1.0e9f;
        vv[2] = q + k4.z + (1.f - a4.z) * -1.0e9f;
        vv[3] = q + k4.w + (1.f - a4.w) * -1.0e9f;
    }
#pragma unroll
    for (int t = 0; t < 16; t++) v[t] = v[t] >= 0.f ? v[t] : 0.01f * v[t];

    float mx = v[0];
#pragma unroll
    for (int t = 1; t < 16; t++) mx = fmaxf(mx, v[t]);
#pragma unroll
    for (int off = 32; off; off >>= 1) mx = fmaxf(mx, __shfl_xor(mx, off));

    float s = 0.f;
#pragma unroll
    for (int t = 0; t < 16; t++) { v[t] = __expf(v[t] - mx); s += v[t]; }
#pragma unroll
    for (int off = 32; off; off >>= 1) s += __shfl_xor(s, off);
    float inv = 1.f / s;

    u16* orow = attb + (size_t)bn * 1024;
#pragma unroll
    for (int c = 0; c < 4; c++) {
        us4 o;
        o.x = f2bf(v[c * 4 + 0] * inv); o.y = f2bf(v[c * 4 + 1] * inv);
        o.z = f2bf(v[c * 4 + 2] * inv); o.w = f2bf(v[c * 4 + 3] * inv);
        *reinterpret_cast<us4*>(orow + c * 256 + lane * 4) = o;
    }
}

extern "C" void kernel_launch(void* const* d_in, const int* in_sizes, int n_in,
                              void* d_out, int out_size, void* d_ws, size_t ws_size,
                              hipStream_t stream) {
    const float* x    = (const float*)d_in[0];
    const float* adj  = (const float*)d_in[1];
    const float* W_fc = (const float*)d_in[2];
    const float* b_fc = (const float*)d_in[3];
    const float* w_q  = (const float*)d_in[4];
    const float* b_q  = (const float*)d_in[5];
    const float* w_k  = (const float*)d_in[6];
    const float* b_k  = (const float*)d_in[7];
    const float* W_uy = (const float*)d_in[8];
    const float* b_uy = (const float*)d_in[9];
    const float* W_ux = (const float*)d_in[10];
    const float* b_ux = (const float*)d_in[11];
    const float* W_ry = (const float*)d_in[12];
    const float* b_ry = (const float*)d_in[13];
    const float* W_rx = (const float*)d_in[14];
    const float* b_rx = (const float*)d_in[15];
    const float* W_ty = (const float*)d_in[16];
    const float* b_ty = (const float*)d_in[17];
    const float* W_tx = (const float*)d_in[18];
    const float* b_tx = (const float*)d_in[19];

    char* ws = (char*)d_ws;
    u16*   CatA  = (u16*)  (ws + 0);            // 16384x1536 bf16  [y | x]   50331648
    u16*   Wfc_b = (u16*)  (ws + 50331648);     //  1179648
    u16*   Wty_b = (u16*)  (ws + 51511296);     //  1179648
    u16*   Wtx_b = (u16*)  (ws + 52690944);     //  1179648
    u16*   Wg    = (u16*)  (ws + 53870592);     // [ [Wuy|Wux] ; [Wry|Wrx] ] 4718592
    u16*   fpT   = (u16*)  (ws + 58589184);     // 16x768x1024 bf16          25165824
    float* qv    = (float*)(ws + 83755008);     // 16384 f32
    float* kv    = (float*)(ws + 83820544);     // 16384 f32
    u16*   attb  = (u16*)  (ws + 83886080);     // 16x1024x1024 bf16         33554432
    u16*   u_b   = (u16*)  (ws + 83886080);     // alias attb (dead after av)
    u16*   rxb   = (u16*)  (ws + 117440512);    // 16384x768 bf16            25165824

    cvtx<<<12288, 256, 0, stream>>>(x, CatA, qv);   // qv,kv contiguous: zeroes both

    WCvt wc;
    wc.s[0] = W_fc; wc.d[0] = Wfc_b;              wc.ld[0] = 768;
    wc.s[1] = W_ty; wc.d[1] = Wty_b;              wc.ld[1] = 768;
    wc.s[2] = W_tx; wc.d[2] = Wtx_b;              wc.ld[2] = 768;
    wc.s[3] = W_uy; wc.d[3] = Wg;                 wc.ld[3] = 1536;
    wc.s[4] = W_ux; wc.d[4] = Wg + 768;           wc.ld[4] = 1536;
    wc.s[5] = W_ry; wc.d[5] = Wg + 768 * 1536;    wc.ld[5] = 1536;
    wc.s[6] = W_rx; wc.d[6] = Wg + 768 * 1536 + 768; wc.ld[6] = 1536;
    cvtw<<<dim3(576, 7), 256, 0, stream>>>(wc);

    Epi e{};
    // feat_proj = x @ Wfc^T + b (A = CatA right half), + fused q/k partials
    e = Epi{}; e.b1 = b_fc; e.wq = w_q; e.wk = w_k; e.qv = qv; e.kv = kv; e.fpT = fpT;
    gFPT<<<dim3(128, 6), 256, 0, stream>>>(CatA + 768, Wfc_b, 768, 1536, 768, e);

    k_soft4<<<4096, 256, 0, stream>>>(adj, qv, kv, b_q, b_k, attb);

    // y = att @ fp  -> CatA left half
    e = Epi{}; e.catA = CatA;
    gY<<<dim3(8, 6, 16), 256, 0, stream>>>(attb, fpT, 1024, 1024, 1024,
                                           1048576, 786432, e);
    // gates: [u | r] = CatA @ [Wuy|Wux ; Wry|Wrx]^T
    e = Epi{}; e.b1 = b_uy; e.b2 = b_ux; e.b3 = b_ry; e.b4 = b_rx;
    e.xb = CatA + 768; e.ub_o = u_b; e.rxb_o = rxb;
    gGATES<<<dim3(128, 12), 256, 0, stream>>>(CatA, Wg, 1536, 1536, 1536, e);

    // out = (1-u)x + u*tanh(y@Wty^T + rx@Wtx^T + b_ty + b_tx)
    e = Epi{}; e.b1 = b_ty; e.b2 = b_tx; e.ub = u_b; e.xb = CatA + 768; e.of = (float*)d_out;
    gOUT<<<dim3(128, 6), 256, 0, stream>>>(CatA, Wty_b, rxb, Wtx_b,
                                           768, 1536, 768, 768, 768, e);
}